// Round 1
// baseline (5016.223 us; speedup 1.0000x reference)
//
#include <hip/hip_runtime.h>
#include <cstdint>
#include <cstddef>

// ---------------------------------------------------------------------------
// LSTMModel: B=128, T=256(->255 diffs), F=6, H=512, L=4, S=32, D=3
// Strategy: layer-wavefront supersteps, bf16 MFMA 16x16x32, fp32 state.
// ---------------------------------------------------------------------------

typedef __bf16 bf16x8 __attribute__((ext_vector_type(8)));
typedef float  f32x4  __attribute__((ext_vector_type(4)));

#define HLS 65536ull            // elems per (slot,layer): 128*512
#define HSS (4ull*HLS)          // elems per slot (4 layers)

// ws byte offsets
#define OFF_H    0ull
#define SZ_H     (256ull*4ull*128ull*512ull*2ull)   // 134217728
#define OFF_D    (OFF_H + SZ_H)
#define SZ_D     524288ull
#define OFF_C    (OFF_D + SZ_D)
#define SZ_C     (4ull*128ull*512ull*4ull)          // 1048576
#define OFF_BIAS (OFF_C + SZ_C)
#define SZ_BIAS  32768ull
#define OFF_BP   (OFF_BIAS + SZ_BIAS)
// bp element offsets (ushort elems) within the BP region
#define BPE_L1   1114112ull      // 128*17*64*8
#define BPE_STR  2097152ull      // 128*32*64*8

__device__ __forceinline__ unsigned short f2bf(float f) {
    unsigned int u = __builtin_bit_cast(unsigned int, f);
    unsigned int lsb = (u >> 16) & 1u;
    u += 0x7fffu + lsb;
    return (unsigned short)(u >> 16);
}
__device__ __forceinline__ float bf2f(unsigned short s) {
    unsigned int u = ((unsigned int)s) << 16;
    return __builtin_bit_cast(float, u);
}
__device__ __forceinline__ float fsig(float x) {
    return 1.0f / (1.0f + __expf(-x));
}
__device__ __forceinline__ float ftanh(float x) {
    float e = __expf(2.0f * x);
    return 1.0f - 2.0f / (e + 1.0f);
}

// ---------------------------------------------------------------------------
// Prep: permute bias columns.  dest col c: gate=(c>>4)&3, j=(c>>6)*16+(c&15)
// ---------------------------------------------------------------------------
__global__ void prep_bias(const float* __restrict__ b, float* __restrict__ bias_ws) {
    int idx = blockIdx.x * 256 + threadIdx.x;
    if (idx >= 4 * 2048) return;
    int l = idx >> 11, c = idx & 2047;
    int j = ((c >> 6) << 4) + (c & 15);
    int gate = (c >> 4) & 3;
    bias_ws[idx] = b[l * 2048 + gate * 512 + j];
}

// ---------------------------------------------------------------------------
// Prep: build weight matrix in MFMA-B-fragment-native layout, bf16.
// Bp[(ct*NKS + ks)*64 + lane][i] = B[k][c],  k = ks*32 + (lane>>4)*8 + i,
// c = ct*16 + (lane&15)   (c is the PERMUTED column index)
// Row sources: layer0: k<8 -> W0 rows (6 real, 2 zero), k in [8,520) -> U0,
//              k>=520 -> 0.   layer>=1: k<512 -> Wk[l-1], else U[l].
// ---------------------------------------------------------------------------
__global__ void prep_bp(int layer, int NKS,
                        const float* __restrict__ W0, const float* __restrict__ Wk,
                        const float* __restrict__ U, unsigned short* __restrict__ bp) {
    int idx = blockIdx.x * 256 + threadIdx.x;
    int total = 128 * NKS * 64;
    if (idx >= total) return;
    int lane = idx & 63;
    int g = lane >> 4, cl = lane & 15;
    int rest = idx >> 6;
    int ks = rest % NKS;
    int ct = rest / NKS;
    int c = ct * 16 + cl;
    int j = ((c >> 6) << 4) + (c & 15);
    int gate = (c >> 4) & 3;
    int sc = gate * 512 + j;
    unsigned short outv[8];
#pragma unroll
    for (int i = 0; i < 8; i++) {
        int k = ks * 32 + g * 8 + i;
        float v = 0.0f;
        if (layer == 0) {
            if (k < 8) { if (k < 6) v = W0[(size_t)k * 2048 + sc]; }
            else if (k < 520) v = U[(size_t)(k - 8) * 2048 + sc];
        } else {
            if (k < 512) v = Wk[((size_t)(layer - 1) * 512 + k) * 2048 + sc];
            else         v = U[((size_t)layer * 512 + (k - 512)) * 2048 + sc];
        }
        outv[i] = f2bf(v);
    }
    *(uint4*)(bp + (size_t)idx * 8) = *(const uint4*)outv;
}

// ---------------------------------------------------------------------------
// Diff: d[t][item][f] = (x[item][t+1][f] - x[item][t][f]) / bound[f], bf16,
// padded to 8 features.
// ---------------------------------------------------------------------------
__global__ void diffk(const float* __restrict__ x, const float* __restrict__ bound,
                      unsigned short* __restrict__ dbuf) {
    int idx = blockIdx.x * 256 + threadIdx.x;
    if (idx >= 255 * 128) return;
    int item = idx & 127, t = idx >> 7;
    const float* xr = x + ((size_t)item * 256 + t) * 6;
    unsigned short row[8];
#pragma unroll
    for (int f = 0; f < 6; f++) row[f] = f2bf((xr[6 + f] - xr[f]) / bound[f]);
    row[6] = 0; row[7] = 0;
    *(uint4*)(dbuf + (size_t)idx * 8) = *(const uint4*)row;
}

// ---------------------------------------------------------------------------
// One wavefront superstep: block = (layer, colgroup cg, m-group mg).
// Computes z[64 items, 64 permuted cols] = A[64,K] @ Bp[K,64], K=1024 (520 l0),
// A = [h_{l-1,t} | h_{l,t-1}] (d | h for layer0), then LSTM cell update.
// ---------------------------------------------------------------------------
__global__ __launch_bounds__(256) void lstm_step(
    int s, unsigned short* __restrict__ hbuf, const unsigned short* __restrict__ dbuf,
    const unsigned short* __restrict__ bp_all, const float* __restrict__ bias,
    float* __restrict__ c_ws)
{
    const int blk = blockIdx.x;
    const int layer = blk >> 6;
    const int cg = (blk >> 1) & 31;
    const int mg = blk & 1;
    const int t = s - layer;
    if (t < 0 || t >= 255) return;

    const int tid  = threadIdx.x;
    const int w    = tid >> 6;
    const int lane = tid & 63;
    const int g    = lane >> 4;
    const int cl   = lane & 15;
    const int NKS  = (layer == 0) ? 17 : 32;
    const size_t bpoff = (layer == 0) ? 0ull : (BPE_L1 + (size_t)(layer - 1) * BPE_STR);
    const unsigned short* bp = bp_all + bpoff;

    __shared__ __align__(16) unsigned short bsm[2][2048];   // 2 x 4KB

    const int ctL = tid >> 6;                       // staging tile 0..3
    const size_t bp_tile = (size_t)(cg * 4 + ctL) * NKS;
    const int aitem = mg * 64 + w * 16 + cl;        // A-fragment row (item)

    auto ld_a = [&](int ks) -> uint4 {
        int k = ks * 32 + g * 8;
        const unsigned short* p;
        if (layer == 0) {
            if (k < 8) {
                p = dbuf + ((size_t)t * 128 + aitem) * 8 + k;
            } else {
                int hk = k - 8; if (hk >= 512) hk = 0;     // zero-weight pad rows
                p = hbuf + (size_t)t * HSS + (size_t)aitem * 512 + hk;
            }
        } else {
            if (k < 512)
                p = hbuf + ((size_t)(t + 1) * 4 + (layer - 1)) * HLS + (size_t)aitem * 512 + k;
            else
                p = hbuf + ((size_t)t * 4 + layer) * HLS + (size_t)aitem * 512 + (k - 512);
        }
        return *(const uint4*)p;
    };
    auto ld_bstage = [&](int ks) -> uint4 {
        return *(const uint4*)(bp + ((bp_tile + ks) * 64 + lane) * 8);
    };

    f32x4 acc[4];
#pragma unroll
    for (int nt = 0; nt < 4; nt++) acc[nt] = (f32x4){0.f, 0.f, 0.f, 0.f};

    uint4 a_cur = ld_a(0);
    uint4 bst = ld_bstage(0);
    *(uint4*)&bsm[0][tid * 8] = bst;
    __syncthreads();

    for (int ks = 0; ks < NKS; ks++) {
        int nk = ks + 1;
        uint4 a_nxt, bst_n;
        if (nk < NKS) { a_nxt = ld_a(nk); bst_n = ld_bstage(nk); }
        bf16x8 av = __builtin_bit_cast(bf16x8, a_cur);
#pragma unroll
        for (int nt = 0; nt < 4; nt++) {
            bf16x8 bv = *(const bf16x8*)&bsm[ks & 1][(nt * 64 + lane) * 8];
            acc[nt] = __builtin_amdgcn_mfma_f32_16x16x32_bf16(av, bv, acc[nt], 0, 0, 0);
        }
        if (nk < NKS) {
            *(uint4*)&bsm[nk & 1][tid * 8] = bst_n;
            __syncthreads();
            a_cur = a_nxt;
        }
    }

    // ---- LSTM cell update: acc[gate][r] all belong to (item(r), j) in-lane
    float bi[4];
#pragma unroll
    for (int nt = 0; nt < 4; nt++) bi[nt] = bias[layer * 2048 + cg * 64 + nt * 16 + cl];
    const int j = cg * 16 + cl;
#pragma unroll
    for (int r = 0; r < 4; r++) {
        int item = mg * 64 + w * 16 + g * 4 + r;
        float zi = acc[0][r] + bi[0];
        float zf = acc[1][r] + bi[1];
        float zg = acc[2][r] + bi[2];
        float zo = acc[3][r] + bi[3];
        float i_ = fsig(zi);
        float f_ = fsig(zf);
        float g_ = ftanh(zg);
        float o_ = fsig(zo);
        size_t cidx = ((size_t)layer * 128 + item) * 512 + j;
        float cn = f_ * c_ws[cidx] + i_ * g_;
        c_ws[cidx] = cn;
        float h = o_ * ftanh(cn);
        hbuf[((size_t)(t + 1) * 4 + layer) * HLS + (size_t)item * 512 + j] = f2bf(h);
    }
}

// ---------------------------------------------------------------------------
// Head: out[b,s,d] = h3[223+s][b] . Wd[:,d] + bd[d];  pred = out*bound+centre
// ---------------------------------------------------------------------------
__global__ void headk(const unsigned short* __restrict__ hbuf,
                      const float* __restrict__ Wd, const float* __restrict__ bd,
                      const float* __restrict__ bound, const float* __restrict__ centre,
                      float* __restrict__ out) {
    int idx = blockIdx.x * 256 + threadIdx.x;
    if (idx >= 12288) return;
    int dd = idx % 3;
    int rest = idx / 3;
    int sdx = rest & 31;
    int b = rest >> 5;
    int t = 223 + sdx;
    const unsigned short* hr = hbuf + ((size_t)(t + 1) * 4 + 3) * HLS + (size_t)b * 512;
    float acc = 0.0f;
    for (int jj = 0; jj < 512; jj++) acc += bf2f(hr[jj]) * Wd[jj * 3 + dd];
    float o = acc + bd[dd];
    out[idx] = o;
    out[12288 + idx] = o * bound[dd] + centre[dd];
}

// ---------------------------------------------------------------------------
extern "C" void kernel_launch(void* const* d_in, const int* in_sizes, int n_in,
                              void* d_out, int out_size, void* d_ws, size_t ws_size,
                              hipStream_t stream) {
    const float* x      = (const float*)d_in[0];
    const float* centre = (const float*)d_in[1];
    const float* bound  = (const float*)d_in[2];
    const float* W0     = (const float*)d_in[3];
    const float* Wk     = (const float*)d_in[4];
    const float* U      = (const float*)d_in[5];
    const float* b      = (const float*)d_in[6];
    const float* Wd     = (const float*)d_in[7];
    const float* bd     = (const float*)d_in[8];

    char* ws = (char*)d_ws;
    unsigned short* hbuf    = (unsigned short*)(ws + OFF_H);
    unsigned short* dbuf    = (unsigned short*)(ws + OFF_D);
    float*          c_ws    = (float*)(ws + OFF_C);
    float*          bias_ws = (float*)(ws + OFF_BIAS);
    unsigned short* bp      = (unsigned short*)(ws + OFF_BP);

    // zero h slot 0 (h_{-1}) and c state
    hipMemsetAsync(hbuf, 0, HSS * 2, stream);
    hipMemsetAsync(c_ws, 0, SZ_C, stream);

    prep_bias<<<32, 256, 0, stream>>>(b, bias_ws);
    prep_bp<<<544, 256, 0, stream>>>(0, 17, W0, Wk, U, bp);
    for (int l = 1; l < 4; l++)
        prep_bp<<<1024, 256, 0, stream>>>(l, 32, W0, Wk, U,
                                          bp + BPE_L1 + (size_t)(l - 1) * BPE_STR);
    diffk<<<128, 256, 0, stream>>>(x, bound, dbuf);

    for (int s = 0; s < 258; s++)
        lstm_step<<<256, 256, 0, stream>>>(s, hbuf, dbuf, bp, bias_ws, c_ws);

    headk<<<48, 256, 0, stream>>>(hbuf, Wd, bd, bound, centre, (float*)d_out);
}